// Round 3
// baseline (5991.256 us; speedup 1.0000x reference)
//
#include <hip/hip_runtime.h>
#include <cstddef>
#include <cstdint>
#include <cmath>

// Problem constants
constexpr int BB = 4, TT = 2048, DD = 768, HH = 8, HD = 96, FF = 2048, LL = 2;
constexpr int MM = BB * TT;             // 8192 rows
constexpr size_t HROW = (size_t)MM * DD; // 6291456

// ---------------------------------------------------------------- LayerNorm
__global__ __launch_bounds__(256)
void layernorm_rows(const float* __restrict__ x, float* __restrict__ y,
                    const float* __restrict__ w, const float* __restrict__ b,
                    const float* mask)
{
    const int row = blockIdx.x;
    const int tid = threadIdx.x;
    const float* xr = x + (size_t)row * DD;
    float v0 = xr[tid], v1 = xr[tid + 256], v2 = xr[tid + 512];
    float s = v0 + v1 + v2;
    float ss = v0 * v0 + v1 * v1 + v2 * v2;
#pragma unroll
    for (int i = 1; i < 64; i <<= 1) { s += __shfl_xor(s, i); ss += __shfl_xor(ss, i); }
    __shared__ float red[8];
    const int wid = tid >> 6, lane = tid & 63;
    if (lane == 0) { red[wid] = s; red[4 + wid] = ss; }
    __syncthreads();
    const float S  = red[0] + red[1] + red[2] + red[3];
    const float SS = red[4] + red[5] + red[6] + red[7];
    const float mean = S * (1.f / DD);
    const float var  = SS * (1.f / DD) - mean * mean;
    const float rstd = rsqrtf(var + 1e-5f);
    const float m = mask ? mask[row] : 1.f;
    float* yr = y + (size_t)row * DD;
    yr[tid]       = ((v0 - mean) * rstd * w[tid]       + b[tid])       * m;
    yr[tid + 256] = ((v1 - mean) * rstd * w[tid + 256] + b[tid + 256]) * m;
    yr[tid + 512] = ((v2 - mean) * rstd * w[tid + 512] + b[tid + 512]) * m;
}

// ---------------------------------------------------------------- GEMM (fp32, 64x64x16 tile)
enum { EPI_NONE = 0, EPI_BIAS, EPI_SILU, EPI_SIGMOID, EPI_EG, EPI_RES, EPI_DUAL };

template <int EPI>
__global__ __launch_bounds__(256)
void gemm_k(const float* __restrict__ A, const float* __restrict__ Bm,
            const float* __restrict__ B2, float* C,
            const float* P0, const float* __restrict__ P1,
            int M, int N, int K)
{
    constexpr bool DUAL = (EPI == EPI_DUAL);
    __shared__ float As[16][64];
    __shared__ float Bs[16][64];
    __shared__ float Bs2[DUAL ? 16 : 1][64];

    const int tid = threadIdx.x;
    const int tx = tid & 15, ty = tid >> 4;
    const int row0 = blockIdx.y * 64;
    const int col0 = blockIdx.x * 64;

    float acc[4][4] = {};
    float acc2[4][4] = {};

    const int ar  = tid >> 2;          // 0..63 (A tile row)
    const int ac4 = (tid & 3) << 2;    // 0,4,8,12 (A tile col base)
    const int br  = tid >> 4;          // 0..15 (B tile row)
    const int bc  = (tid & 15) << 2;   // 0..60 (B tile col base)
    const int gc  = col0 + bc;
    const bool bok = gc < N;           // all N here are multiples of 4

    for (int kt = 0; kt < K; kt += 16) {
        const float4 a4 = *(const float4*)(A + (size_t)(row0 + ar) * K + kt + ac4);
        float4 b4 = make_float4(0.f, 0.f, 0.f, 0.f);
        float4 c4 = make_float4(0.f, 0.f, 0.f, 0.f);
        if (bok) b4 = *(const float4*)(Bm + (size_t)(kt + br) * N + gc);
        if constexpr (DUAL) { if (bok) c4 = *(const float4*)(B2 + (size_t)(kt + br) * N + gc); }
        __syncthreads();
        As[ac4 + 0][ar] = a4.x; As[ac4 + 1][ar] = a4.y;
        As[ac4 + 2][ar] = a4.z; As[ac4 + 3][ar] = a4.w;
        *(float4*)&Bs[br][bc] = b4;
        if constexpr (DUAL) *(float4*)&Bs2[br][bc] = c4;
        __syncthreads();
#pragma unroll
        for (int kk = 0; kk < 16; ++kk) {
            const float4 av = *(const float4*)&As[kk][ty << 2];
            const float4 bv = *(const float4*)&Bs[kk][tx << 2];
            const float a_[4] = {av.x, av.y, av.z, av.w};
            const float b_[4] = {bv.x, bv.y, bv.z, bv.w};
            if constexpr (DUAL) {
                const float4 cv = *(const float4*)&Bs2[kk][tx << 2];
                const float c_[4] = {cv.x, cv.y, cv.z, cv.w};
#pragma unroll
                for (int i = 0; i < 4; ++i)
#pragma unroll
                    for (int j = 0; j < 4; ++j) {
                        acc[i][j]  = fmaf(a_[i], b_[j], acc[i][j]);
                        acc2[i][j] = fmaf(a_[i], c_[j], acc2[i][j]);
                    }
            } else {
#pragma unroll
                for (int i = 0; i < 4; ++i)
#pragma unroll
                    for (int j = 0; j < 4; ++j)
                        acc[i][j] = fmaf(a_[i], b_[j], acc[i][j]);
            }
        }
    }

#pragma unroll
    for (int i = 0; i < 4; ++i) {
        const int row = row0 + (ty << 2) + i;
#pragma unroll
        for (int j = 0; j < 4; ++j) {
            const int col = col0 + (tx << 2) + j;
            if (col >= N) continue;
            const size_t idx = (size_t)row * N + col;
            float val = acc[i][j];
            if constexpr (EPI == EPI_BIAS) {
                val += P0[col];
            } else if constexpr (EPI == EPI_SILU) {
                val = val / (1.f + expf(-val));
            } else if constexpr (EPI == EPI_SIGMOID) {
                val = 1.f / (1.f + expf(-val));
            } else if constexpr (EPI == EPI_EG) {
                const float lin = val + P1[col];
                const float sp = (lin > 20.f) ? lin : log1pf(expf(lin));
                val = expf(-expf(P0[col]) * sp);
            } else if constexpr (EPI == EPI_RES) {
                val += P0[idx];
            } else if constexpr (EPI == EPI_DUAL) {
                val = (val / (1.f + expf(-val))) * acc2[i][j];
            }
            C[idx] = val;
        }
    }
}

// ---------------------------------------------------------------- row ops over HD=96
__global__ __launch_bounds__(256)
void l2norm_rows(float* x, float scale)
{
    const int row  = (blockIdx.x << 2) + (threadIdx.x >> 6);
    const int lane = threadIdx.x & 63;
    float* xr = x + (size_t)row * HD;
    const float a = xr[lane];
    const float b = (lane < 32) ? xr[64 + lane] : 0.f;
    float ss = a * a + b * b;
#pragma unroll
    for (int i = 1; i < 64; i <<= 1) ss += __shfl_xor(ss, i);
    const float r = rsqrtf(ss + 1e-6f) * scale;
    xr[lane] = a * r;
    if (lane < 32) xr[64 + lane] = b * r;
}

__global__ __launch_bounds__(256)
void onorm_gate_k(float* o, const float* __restrict__ gate, const float* __restrict__ w)
{
    const int row  = (blockIdx.x << 2) + (threadIdx.x >> 6);
    const int lane = threadIdx.x & 63;
    float* orow = o + (size_t)row * HD;
    const float* grow = gate + (size_t)row * HD;
    const float a = orow[lane];
    const float b = (lane < 32) ? orow[64 + lane] : 0.f;
    float ss = a * a + b * b;
#pragma unroll
    for (int i = 1; i < 64; i <<= 1) ss += __shfl_xor(ss, i);
    const float r = rsqrtf(ss * (1.f / HD) + 1e-6f);
    const float g0 = grow[lane];
    orow[lane] = a * r * w[lane] * (g0 / (1.f + expf(-g0)));
    if (lane < 32) {
        const float g1 = grow[64 + lane];
        orow[64 + lane] = b * r * w[64 + lane] * (g1 / (1.f + expf(-g1)));
    }
}

// ---------------------------------------------------------------- KDA scan
// grid: 64 blocks = (b*8+h)*2 + vhalf ; block: 192 threads = 48 vcols x 4 kgroups
// State S[k,v] per (b,h): thread owns column vcol, k-slice [kg*24, kg*24+24).
// o may alias q (q row t is consumed in the staging of the chunk containing t,
// strictly before o row t is written; both separated by __syncthreads).
constexpr int SCH = 16;
__global__ __launch_bounds__(192)
void kda_scan(const float* q, const float* __restrict__ k,
              const float* __restrict__ v, const float* __restrict__ eg,
              const float* __restrict__ beta, float* o, float* states)
{
    const int blk  = blockIdx.x;
    const int pair = blk >> 1;           // b*8+h
    const int vh   = blk & 1;
    const int b    = pair >> 3, h = pair & 7;
    const int tid  = threadIdx.x;
    const int vloc = tid >> 2;           // 0..47
    const int kg   = tid & 3;
    const int vcol = vh * 48 + vloc;
    const int k0   = kg * 24;

    __shared__ float sk[SCH][HD];
    __shared__ float sq[SCH][HD];
    __shared__ float se[SCH][HD];
    __shared__ float sv[SCH][HD];
    __shared__ float sb[SCH];

    const size_t base  = ((size_t)b * TT * HH + h) * HD;   // + t*768 + c
    const size_t bbase = (size_t)b * TT * HH + h;          // beta: + t*8

    float S[24];
#pragma unroll
    for (int j = 0; j < 24; ++j) S[j] = 0.f;

    for (int t0 = 0; t0 < TT; t0 += SCH) {
        __syncthreads();
        for (int i = tid; i < SCH * 24; i += 192) {  // 384 float4 per array
            const int s = i / 24, c4 = (i % 24) * 4;
            const size_t g = base + (size_t)(t0 + s) * (HH * HD) + c4;
            *(float4*)&sk[s][c4] = *(const float4*)(k + g);
            *(float4*)&sq[s][c4] = *(const float4*)(q + g);
            *(float4*)&se[s][c4] = *(const float4*)(eg + g);
            *(float4*)&sv[s][c4] = *(const float4*)(v + g);
        }
        if (tid < SCH) sb[tid] = beta[bbase + (size_t)(t0 + tid) * HH];
        __syncthreads();

        for (int s = 0; s < SCH; ++s) {
            float kk_[24], ee[24], qq[24];
#pragma unroll
            for (int j4 = 0; j4 < 6; ++j4) {
                *(float4*)&kk_[j4 * 4] = *(const float4*)&sk[s][k0 + j4 * 4];
                *(float4*)&ee[j4 * 4]  = *(const float4*)&se[s][k0 + j4 * 4];
                *(float4*)&qq[j4 * 4]  = *(const float4*)&sq[s][k0 + j4 * 4];
            }
            float kv = 0.f;
#pragma unroll
            for (int j = 0; j < 24; ++j) { S[j] *= ee[j]; kv = fmaf(S[j], kk_[j], kv); }
            kv += __shfl_xor(kv, 1);
            kv += __shfl_xor(kv, 2);
            const float delta = (sv[s][vcol] - kv) * sb[s];
            float oo = 0.f;
#pragma unroll
            for (int j = 0; j < 24; ++j) { S[j] = fmaf(kk_[j], delta, S[j]); oo = fmaf(qq[j], S[j], oo); }
            oo += __shfl_xor(oo, 1);
            oo += __shfl_xor(oo, 2);
            if (kg == 0) o[base + (size_t)(t0 + s) * (HH * HD) + vcol] = oo;
        }
    }
    // states[b,h,k,v]
    float* sp = states + (size_t)pair * (HD * HD);
#pragma unroll
    for (int j = 0; j < 24; ++j) sp[(size_t)(k0 + j) * HD + vcol] = S[j];
}

// ---------------------------------------------------------------- host
static inline void launch_gemm(int epi, hipStream_t st,
                               const float* A, const float* Bm, const float* B2, float* C,
                               const float* P0, const float* P1, int M, int N, int K)
{
    dim3 grid((N + 63) / 64, M / 64), blk(256);
    switch (epi) {
    case EPI_NONE:    gemm_k<EPI_NONE><<<grid, blk, 0, st>>>(A, Bm, B2, C, P0, P1, M, N, K); break;
    case EPI_BIAS:    gemm_k<EPI_BIAS><<<grid, blk, 0, st>>>(A, Bm, B2, C, P0, P1, M, N, K); break;
    case EPI_SILU:    gemm_k<EPI_SILU><<<grid, blk, 0, st>>>(A, Bm, B2, C, P0, P1, M, N, K); break;
    case EPI_SIGMOID: gemm_k<EPI_SIGMOID><<<grid, blk, 0, st>>>(A, Bm, B2, C, P0, P1, M, N, K); break;
    case EPI_EG:      gemm_k<EPI_EG><<<grid, blk, 0, st>>>(A, Bm, B2, C, P0, P1, M, N, K); break;
    case EPI_RES:     gemm_k<EPI_RES><<<grid, blk, 0, st>>>(A, Bm, B2, C, P0, P1, M, N, K); break;
    case EPI_DUAL:    gemm_k<EPI_DUAL><<<grid, blk, 0, st>>>(A, Bm, B2, C, P0, P1, M, N, K); break;
    }
}

extern "C" void kernel_launch(void* const* d_in, const int* in_sizes, int n_in,
                              void* d_out, int out_size, void* d_ws, size_t ws_size,
                              hipStream_t stream)
{
    (void)in_sizes; (void)n_in; (void)out_size;
    const float* hidden   = (const float*)d_in[0];
    const float* mask     = (const float*)d_in[1];
    const float* norm_a_w = (const float*)d_in[2];
    const float* norm_a_b = (const float*)d_in[3];
    const float* proj_a_w = (const float*)d_in[4];
    const float* proj_a_b = (const float*)d_in[5];
    const float* ln_w     = (const float*)d_in[6];
    const float* ln_b     = (const float*)d_in[7];
    const float* Wq       = (const float*)d_in[8];
    const float* Wk       = (const float*)d_in[9];
    const float* Wv       = (const float*)d_in[10];
    const float* Wfa      = (const float*)d_in[11];
    const float* Wfb      = (const float*)d_in[12];
    const float* dt_bias  = (const float*)d_in[13];
    const float* A_log    = (const float*)d_in[14];
    const float* Wb       = (const float*)d_in[15];
    const float* Wga      = (const float*)d_in[16];
    const float* Wgb      = (const float*)d_in[17];
    const float* onorm_w  = (const float*)d_in[18];
    const float* Wo       = (const float*)d_in[19];
    const float* Wgate    = (const float*)d_in[20];
    const float* Wup      = (const float*)d_in[21];
    const float* Wdown    = (const float*)d_in[22];

    float* ws = (float*)d_ws;
    float* x    = ws;                     // 6291456  (hn / a_out)
    float* hbuf = ws + HROW;              // 6291456
    float* qb   = ws + 2 * HROW;          // 6291456  (also o)
    float* kb   = ws + 3 * HROW;          // 6291456
    float* vb   = ws + 4 * HROW;          // 6291456  (also gate)
    float* egb  = ws + 5 * HROW;          // 6291456
    float* mgb  = ws + 6 * HROW;          // 8388608 (half-M swiglu buffer)
    float* fab  = mgb + (size_t)4096 * FF;// 786432 (fa / ga)
    float* betab= fab + (size_t)MM * HD;  // 65536
    (void)ws_size;

    float* out    = (float*)d_out;
    float* states = out + HROW;

    // h = LN(hidden) @ proj_a_w + proj_a_b
    layernorm_rows<<<MM, 256, 0, stream>>>(hidden, x, norm_a_w, norm_a_b, nullptr);
    launch_gemm(EPI_BIAS, stream, x, proj_a_w, nullptr, hbuf, proj_a_b, nullptr, MM, DD, DD);

    for (int l = 0; l < LL; ++l) {
        const float* Wq_l  = Wq  + (size_t)l * DD * DD;
        const float* Wk_l  = Wk  + (size_t)l * DD * DD;
        const float* Wv_l  = Wv  + (size_t)l * DD * DD;
        const float* Wfa_l = Wfa + (size_t)l * DD * HD;
        const float* Wfb_l = Wfb + (size_t)l * HD * DD;
        const float* Wb_l  = Wb  + (size_t)l * DD * HH;
        const float* Wga_l = Wga + (size_t)l * DD * HD;
        const float* Wgb_l = Wgb + (size_t)l * HD * DD;
        const float* Wo_l  = Wo  + (size_t)l * DD * DD;
        const float* Wg_l  = Wgate + (size_t)l * DD * FF;
        const float* Wu_l  = Wup   + (size_t)l * DD * FF;
        const float* Wd_l  = Wdown + (size_t)l * FF * DD;

        // x = LN(h) * mask
        layernorm_rows<<<MM, 256, 0, stream>>>(hbuf, x, ln_w + l * DD, ln_b + l * DD, mask);
        // q,k,v = silu(x@W)
        launch_gemm(EPI_SILU, stream, x, Wq_l, nullptr, qb, nullptr, nullptr, MM, DD, DD);
        launch_gemm(EPI_SILU, stream, x, Wk_l, nullptr, kb, nullptr, nullptr, MM, DD, DD);
        launch_gemm(EPI_SILU, stream, x, Wv_l, nullptr, vb, nullptr, nullptr, MM, DD, DD);
        // l2norm per (b,t,h); q scaled by HD^-0.5
        l2norm_rows<<<(MM * HH) / 4, 256, 0, stream>>>(qb, 0.1020620726159658f);
        l2norm_rows<<<(MM * HH) / 4, 256, 0, stream>>>(kb, 1.f);
        // eg = exp(-exp(A_log) * softplus((x@Wfa)@Wfb + dt_bias))
        launch_gemm(EPI_NONE, stream, x, Wfa_l, nullptr, fab, nullptr, nullptr, MM, HD, DD);
        launch_gemm(EPI_EG, stream, fab, Wfb_l, nullptr, egb, A_log + l * DD, dt_bias + l * DD, MM, DD, HD);
        // beta = sigmoid(x@Wb)
        launch_gemm(EPI_SIGMOID, stream, x, Wb_l, nullptr, betab, nullptr, nullptr, MM, HH, DD);
        // scan: o (aliases qb), states
        kda_scan<<<64, 192, 0, stream>>>(qb, kb, vb, egb, betab, qb,
                                         states + (size_t)l * BB * HH * HD * HD);
        // gate = (x@Wga)@Wgb (into vb; v consumed by scan)
        launch_gemm(EPI_NONE, stream, x, Wga_l, nullptr, fab, nullptr, nullptr, MM, HD, DD);
        launch_gemm(EPI_NONE, stream, fab, Wgb_l, nullptr, vb, nullptr, nullptr, MM, DD, HD);
        // o = o*rsqrt(mean o^2 + eps)*onorm_w * silu(gate)
        onorm_gate_k<<<(MM * HH) / 4, 256, 0, stream>>>(qb, vb, onorm_w + l * HD);
        // a = o @ Wo  (into x)
        launch_gemm(EPI_NONE, stream, qb, Wo_l, nullptr, x, nullptr, nullptr, MM, DD, DD);
        // swiglu + down + residual, M chunked in halves to bound mg buffer
        float* dst = (l == LL - 1) ? out : hbuf;
        for (int mh = 0; mh < 2; ++mh) {
            const float* Ax = x + (size_t)mh * 4096 * DD;
            launch_gemm(EPI_DUAL, stream, Ax, Wg_l, Wu_l, mgb, nullptr, nullptr, 4096, FF, DD);
            launch_gemm(EPI_RES, stream, mgb, Wd_l, nullptr,
                        dst + (size_t)mh * 4096 * DD,
                        hbuf + (size_t)mh * 4096 * DD, nullptr, 4096, DD, FF);
        }
    }
}

// Round 4
// 3095.583 us; speedup vs baseline: 1.9354x; 1.9354x over previous
//
#include <hip/hip_runtime.h>
#include <cstddef>
#include <cstdint>
#include <cmath>

// Problem constants
constexpr int BB = 4, TT = 2048, DD = 768, HH = 8, HD = 96, FF = 2048, LL = 2;
constexpr int MM = BB * TT;              // 8192
constexpr size_t HROW = (size_t)MM * DD; // 6291456

typedef float f32x4 __attribute__((ext_vector_type(4)));
typedef short bf16x8 __attribute__((ext_vector_type(8)));

__device__ __forceinline__ void gload16(const void* g, void* l) {
    __builtin_amdgcn_global_load_lds(
        (const __attribute__((address_space(1))) void*)g,
        (__attribute__((address_space(3))) void*)l, 16, 0, 0);
}
__device__ __forceinline__ float bf2f(unsigned short u) {
    return __uint_as_float(((unsigned)u) << 16);
}
__device__ __forceinline__ unsigned short f2bf(float f) {
    unsigned u = __float_as_uint(f);
    unsigned r = (u + 0x7fffu + ((u >> 16) & 1u)) >> 16;
    return (unsigned short)r;
}

// ---------------------------------------------------------------- LayerNorm -> bf16
__global__ __launch_bounds__(256)
void layernorm_rows(const float* __restrict__ x, unsigned short* __restrict__ y,
                    const float* __restrict__ w, const float* __restrict__ b,
                    const float* mask)
{
    const int row = blockIdx.x;
    const int tid = threadIdx.x;
    const float* xr = x + (size_t)row * DD;
    float v0 = xr[tid], v1 = xr[tid + 256], v2 = xr[tid + 512];
    float s = v0 + v1 + v2;
    float ss = v0 * v0 + v1 * v1 + v2 * v2;
#pragma unroll
    for (int i = 1; i < 64; i <<= 1) { s += __shfl_xor(s, i); ss += __shfl_xor(ss, i); }
    __shared__ float red[8];
    const int wid = tid >> 6, lane = tid & 63;
    if (lane == 0) { red[wid] = s; red[4 + wid] = ss; }
    __syncthreads();
    const float S  = red[0] + red[1] + red[2] + red[3];
    const float SS = red[4] + red[5] + red[6] + red[7];
    const float mean = S * (1.f / DD);
    const float var  = SS * (1.f / DD) - mean * mean;
    const float rstd = rsqrtf(var + 1e-5f);
    const float m = mask ? mask[row] : 1.f;
    unsigned short* yr = y + (size_t)row * DD;
    yr[tid]       = f2bf(((v0 - mean) * rstd * w[tid]       + b[tid])       * m);
    yr[tid + 256] = f2bf(((v1 - mean) * rstd * w[tid + 256] + b[tid + 256]) * m);
    yr[tid + 512] = f2bf(((v2 - mean) * rstd * w[tid + 512] + b[tid + 512]) * m);
}

// ---------------------------------------------------------------- transpose+convert W
// in: fp32 [K][N], out: bf16 [N][K]. K,N multiples of 32.
__global__ __launch_bounds__(256)
void transcvt(const float* __restrict__ in, unsigned short* __restrict__ out, int K, int N)
{
    __shared__ float t[32][33];
    const int tx = threadIdx.x & 31, ty = threadIdx.x >> 5;
    const int k0 = blockIdx.y * 32, n0 = blockIdx.x * 32;
#pragma unroll
    for (int i = 0; i < 4; ++i)
        t[ty + i * 8][tx] = in[(size_t)(k0 + ty + i * 8) * N + n0 + tx];
    __syncthreads();
#pragma unroll
    for (int i = 0; i < 4; ++i)
        out[(size_t)(n0 + ty + i * 8) * K + k0 + tx] = f2bf(t[tx][ty + i * 8]);
}

// ---------------------------------------------------------------- bf16 MFMA GEMM
// A [M][K] bf16, Bt [N][K] bf16. Tile 128x128x32, 4 waves, 4x4 16x16x32 frags.
enum { BE_BIAS = 0, BE_SILU, BE_EG, BE_F32, BE_BF16, BE_RES };

template <int EPI>
__global__ __launch_bounds__(256)
void bgemm(const unsigned short* __restrict__ A, const unsigned short* __restrict__ Bt,
           float* Cf, unsigned short* Cb,
           const float* P0, const float* __restrict__ P1,
           int M, int N, int K)
{
    __shared__ unsigned short As[128 * 32];
    __shared__ unsigned short Bs[128 * 32];
    const int tid = threadIdx.x;
    const int w = tid >> 6, l = tid & 63;
    const int wm = w >> 1, wn = w & 1;
    const int lr = l & 15, lh = l >> 4;
    const int m0 = blockIdx.y * 128, n0 = blockIdx.x * 128;

    f32x4 acc[4][4];
#pragma unroll
    for (int i = 0; i < 4; ++i)
#pragma unroll
        for (int j = 0; j < 4; ++j) acc[i][j] = (f32x4){0.f, 0.f, 0.f, 0.f};

    const int sr = l >> 2, sq = (l & 3) * 8;
    const unsigned short* Ag = A + (size_t)(m0 + w * 32 + sr) * K + sq;
    const unsigned short* Bg = Bt + (size_t)(n0 + w * 32 + sr) * K + sq;
    unsigned short* Al = &As[(w * 32) * 32];
    unsigned short* Bl = &Bs[(w * 32) * 32];

    for (int kt = 0; kt < K; kt += 32) {
        __syncthreads();
        gload16(Ag + kt, Al);
        gload16(Ag + kt + 16 * (size_t)K, Al + 16 * 32);
        gload16(Bg + kt, Bl);
        gload16(Bg + kt + 16 * (size_t)K, Bl + 16 * 32);
        __syncthreads();
        bf16x8 af[4], bfv[4];
#pragma unroll
        for (int mi = 0; mi < 4; ++mi)
            af[mi] = *(const bf16x8*)&As[(wm * 64 + mi * 16 + lr) * 32 + lh * 8];
#pragma unroll
        for (int ni = 0; ni < 4; ++ni)
            bfv[ni] = *(const bf16x8*)&Bs[(wn * 64 + ni * 16 + lr) * 32 + lh * 8];
#pragma unroll
        for (int mi = 0; mi < 4; ++mi)
#pragma unroll
            for (int ni = 0; ni < 4; ++ni)
                acc[mi][ni] = __builtin_amdgcn_mfma_f32_16x16x32_bf16(af[mi], bfv[ni], acc[mi][ni], 0, 0, 0);
    }

#pragma unroll
    for (int mi = 0; mi < 4; ++mi) {
#pragma unroll
        for (int j = 0; j < 4; ++j) {
            const int row = m0 + wm * 64 + mi * 16 + lh * 4 + j;
#pragma unroll
            for (int ni = 0; ni < 4; ++ni) {
                const int col = n0 + wn * 64 + ni * 16 + lr;
                const size_t idx = (size_t)row * N + col;
                float v = acc[mi][ni][j];
                if constexpr (EPI == BE_BIAS) { Cf[idx] = v + P0[col]; }
                else if constexpr (EPI == BE_SILU) { Cf[idx] = v / (1.f + expf(-v)); }
                else if constexpr (EPI == BE_EG) {
                    const float lin = v + P1[col];
                    const float sp = (lin > 20.f) ? lin : log1pf(expf(lin));
                    Cf[idx] = expf(-expf(P0[col]) * sp);
                }
                else if constexpr (EPI == BE_F32) { Cf[idx] = v; }
                else if constexpr (EPI == BE_BF16) { Cb[idx] = f2bf(v); }
                else if constexpr (EPI == BE_RES) { Cf[idx] = v + P0[idx]; }
            }
        }
    }
}

// Dual-B GEMM for SwiGLU: C = bf16( silu(A@Wg) * (A@Wu) ). Tile 128x64x32.
__global__ __launch_bounds__(256)
void bgemm_dual(const unsigned short* __restrict__ A,
                const unsigned short* __restrict__ Bg_, const unsigned short* __restrict__ Bu_,
                unsigned short* __restrict__ C, int M, int N, int K)
{
    __shared__ unsigned short As[128 * 32];
    __shared__ unsigned short Bs1[64 * 32];
    __shared__ unsigned short Bs2[64 * 32];
    const int tid = threadIdx.x;
    const int w = tid >> 6, l = tid & 63;
    const int wm = w >> 1, wn = w & 1;
    const int lr = l & 15, lh = l >> 4;
    const int m0 = blockIdx.y * 128, n0 = blockIdx.x * 64;

    f32x4 a1[4][2], a2[4][2];
#pragma unroll
    for (int i = 0; i < 4; ++i)
#pragma unroll
        for (int j = 0; j < 2; ++j) { a1[i][j] = (f32x4){0.f,0.f,0.f,0.f}; a2[i][j] = (f32x4){0.f,0.f,0.f,0.f}; }

    const int sr = l >> 2, sq = (l & 3) * 8;
    const unsigned short* Ag  = A   + (size_t)(m0 + w * 32 + sr) * K + sq;
    const unsigned short* B1g = Bg_ + (size_t)(n0 + w * 16 + sr) * K + sq;
    const unsigned short* B2g = Bu_ + (size_t)(n0 + w * 16 + sr) * K + sq;
    unsigned short* Al  = &As[(w * 32) * 32];
    unsigned short* B1l = &Bs1[(w * 16) * 32];
    unsigned short* B2l = &Bs2[(w * 16) * 32];

    for (int kt = 0; kt < K; kt += 32) {
        __syncthreads();
        gload16(Ag + kt, Al);
        gload16(Ag + kt + 16 * (size_t)K, Al + 16 * 32);
        gload16(B1g + kt, B1l);
        gload16(B2g + kt, B2l);
        __syncthreads();
        bf16x8 af[4], b1[2], b2[2];
#pragma unroll
        for (int mi = 0; mi < 4; ++mi)
            af[mi] = *(const bf16x8*)&As[(wm * 64 + mi * 16 + lr) * 32 + lh * 8];
#pragma unroll
        for (int ni = 0; ni < 2; ++ni) {
            b1[ni] = *(const bf16x8*)&Bs1[(wn * 32 + ni * 16 + lr) * 32 + lh * 8];
            b2[ni] = *(const bf16x8*)&Bs2[(wn * 32 + ni * 16 + lr) * 32 + lh * 8];
        }
#pragma unroll
        for (int mi = 0; mi < 4; ++mi)
#pragma unroll
            for (int ni = 0; ni < 2; ++ni) {
                a1[mi][ni] = __builtin_amdgcn_mfma_f32_16x16x32_bf16(af[mi], b1[ni], a1[mi][ni], 0, 0, 0);
                a2[mi][ni] = __builtin_amdgcn_mfma_f32_16x16x32_bf16(af[mi], b2[ni], a2[mi][ni], 0, 0, 0);
            }
    }

#pragma unroll
    for (int mi = 0; mi < 4; ++mi)
#pragma unroll
        for (int j = 0; j < 4; ++j) {
            const int row = m0 + wm * 64 + mi * 16 + lh * 4 + j;
#pragma unroll
            for (int ni = 0; ni < 2; ++ni) {
                const int col = n0 + wn * 32 + ni * 16 + lr;
                const float g = a1[mi][ni][j], u = a2[mi][ni][j];
                C[(size_t)row * N + col] = f2bf((g / (1.f + expf(-g))) * u);
            }
        }
}

// ---------------------------------------------------------------- small fp32 GEMM (A bf16)
// MODE 0: C=bf16, no act (fa/ga). MODE 1: C=f32, sigmoid (beta).
template <int MODE>
__global__ __launch_bounds__(256)
void gemm_small(const unsigned short* __restrict__ A, const float* __restrict__ Bm,
                unsigned short* Cb, float* Cf, int M, int N, int K)
{
    __shared__ float As[16][64];
    __shared__ float Bs[16][64];
    const int tid = threadIdx.x;
    const int tx = tid & 15, ty = tid >> 4;
    const int row0 = blockIdx.y * 64;
    const int col0 = blockIdx.x * 64;
    float acc[4][4] = {};
    const int ar  = tid >> 2;
    const int ac4 = (tid & 3) << 2;
    const int br  = tid >> 4;
    const int bc  = (tid & 15) << 2;
    const int gc  = col0 + bc;
    const bool bok = gc < N;

    for (int kt = 0; kt < K; kt += 16) {
        const ushort4 a4 = *(const ushort4*)(A + (size_t)(row0 + ar) * K + kt + ac4);
        float4 b4 = make_float4(0.f, 0.f, 0.f, 0.f);
        if (bok) b4 = *(const float4*)(Bm + (size_t)(kt + br) * N + gc);
        __syncthreads();
        As[ac4 + 0][ar] = bf2f(a4.x); As[ac4 + 1][ar] = bf2f(a4.y);
        As[ac4 + 2][ar] = bf2f(a4.z); As[ac4 + 3][ar] = bf2f(a4.w);
        *(float4*)&Bs[br][bc] = b4;
        __syncthreads();
#pragma unroll
        for (int kk = 0; kk < 16; ++kk) {
            const float4 av = *(const float4*)&As[kk][ty << 2];
            const float4 bv = *(const float4*)&Bs[kk][tx << 2];
            const float a_[4] = {av.x, av.y, av.z, av.w};
            const float b_[4] = {bv.x, bv.y, bv.z, bv.w};
#pragma unroll
            for (int i = 0; i < 4; ++i)
#pragma unroll
                for (int j = 0; j < 4; ++j)
                    acc[i][j] = fmaf(a_[i], b_[j], acc[i][j]);
        }
    }
#pragma unroll
    for (int i = 0; i < 4; ++i) {
        const int row = row0 + (ty << 2) + i;
#pragma unroll
        for (int j = 0; j < 4; ++j) {
            const int col = col0 + (tx << 2) + j;
            if (col >= N) continue;
            const size_t idx = (size_t)row * N + col;
            if constexpr (MODE == 0) Cb[idx] = f2bf(acc[i][j]);
            else                     Cf[idx] = 1.f / (1.f + expf(-acc[i][j]));
        }
    }
}

// ---------------------------------------------------------------- row ops over HD=96
__global__ __launch_bounds__(256)
void l2norm_rows(float* x, float scale)
{
    const int row  = (blockIdx.x << 2) + (threadIdx.x >> 6);
    const int lane = threadIdx.x & 63;
    float* xr = x + (size_t)row * HD;
    const float a = xr[lane];
    const float b = (lane < 32) ? xr[64 + lane] : 0.f;
    float ss = a * a + b * b;
#pragma unroll
    for (int i = 1; i < 64; i <<= 1) ss += __shfl_xor(ss, i);
    const float r = rsqrtf(ss + 1e-6f) * scale;
    xr[lane] = a * r;
    if (lane < 32) xr[64 + lane] = b * r;
}

__global__ __launch_bounds__(256)
void onorm_gate_k(const float* __restrict__ o, const float* __restrict__ gate,
                  const float* __restrict__ w, unsigned short* __restrict__ outb)
{
    const int row  = (blockIdx.x << 2) + (threadIdx.x >> 6);
    const int lane = threadIdx.x & 63;
    const float* orow = o + (size_t)row * HD;
    const float* grow = gate + (size_t)row * HD;
    unsigned short* yr = outb + (size_t)row * HD;
    const float a = orow[lane];
    const float b = (lane < 32) ? orow[64 + lane] : 0.f;
    float ss = a * a + b * b;
#pragma unroll
    for (int i = 1; i < 64; i <<= 1) ss += __shfl_xor(ss, i);
    const float r = rsqrtf(ss * (1.f / HD) + 1e-6f);
    const float g0 = grow[lane];
    yr[lane] = f2bf(a * r * w[lane] * (g0 / (1.f + expf(-g0))));
    if (lane < 32) {
        const float g1 = grow[64 + lane];
        yr[64 + lane] = f2bf(b * r * w[64 + lane] * (g1 / (1.f + expf(-g1))));
    }
}

// ---------------------------------------------------------------- KDA scan (unchanged)
constexpr int SCH = 16;
__global__ __launch_bounds__(192)
void kda_scan(const float* q, const float* __restrict__ k,
              const float* __restrict__ v, const float* __restrict__ eg,
              const float* __restrict__ beta, float* o, float* states)
{
    const int blk  = blockIdx.x;
    const int pair = blk >> 1;
    const int vh   = blk & 1;
    const int b    = pair >> 3, h = pair & 7;
    const int tid  = threadIdx.x;
    const int vloc = tid >> 2;
    const int kg   = tid & 3;
    const int vcol = vh * 48 + vloc;
    const int k0   = kg * 24;

    __shared__ float sk[SCH][HD];
    __shared__ float sq[SCH][HD];
    __shared__ float se[SCH][HD];
    __shared__ float sv[SCH][HD];
    __shared__ float sb[SCH];

    const size_t base  = ((size_t)b * TT * HH + h) * HD;
    const size_t bbase = (size_t)b * TT * HH + h;

    float S[24];
#pragma unroll
    for (int j = 0; j < 24; ++j) S[j] = 0.f;

    for (int t0 = 0; t0 < TT; t0 += SCH) {
        __syncthreads();
        for (int i = tid; i < SCH * 24; i += 192) {
            const int s = i / 24, c4 = (i % 24) * 4;
            const size_t g = base + (size_t)(t0 + s) * (HH * HD) + c4;
            *(float4*)&sk[s][c4] = *(const float4*)(k + g);
            *(float4*)&sq[s][c4] = *(const float4*)(q + g);
            *(float4*)&se[s][c4] = *(const float4*)(eg + g);
            *(float4*)&sv[s][c4] = *(const float4*)(v + g);
        }
        if (tid < SCH) sb[tid] = beta[bbase + (size_t)(t0 + tid) * HH];
        __syncthreads();

        for (int s = 0; s < SCH; ++s) {
            float kk_[24], ee[24], qq[24];
#pragma unroll
            for (int j4 = 0; j4 < 6; ++j4) {
                *(float4*)&kk_[j4 * 4] = *(const float4*)&sk[s][k0 + j4 * 4];
                *(float4*)&ee[j4 * 4]  = *(const float4*)&se[s][k0 + j4 * 4];
                *(float4*)&qq[j4 * 4]  = *(const float4*)&sq[s][k0 + j4 * 4];
            }
            float kv = 0.f;
#pragma unroll
            for (int j = 0; j < 24; ++j) { S[j] *= ee[j]; kv = fmaf(S[j], kk_[j], kv); }
            kv += __shfl_xor(kv, 1);
            kv += __shfl_xor(kv, 2);
            const float delta = (sv[s][vcol] - kv) * sb[s];
            float oo = 0.f;
#pragma unroll
            for (int j = 0; j < 24; ++j) { S[j] = fmaf(kk_[j], delta, S[j]); oo = fmaf(qq[j], S[j], oo); }
            oo += __shfl_xor(oo, 1);
            oo += __shfl_xor(oo, 2);
            if (kg == 0) o[base + (size_t)(t0 + s) * (HH * HD) + vcol] = oo;
        }
    }
    float* sp = states + (size_t)pair * (HD * HD);
#pragma unroll
    for (int j = 0; j < 24; ++j) sp[(size_t)(k0 + j) * HD + vcol] = S[j];
}

// ---------------------------------------------------------------- host
extern "C" void kernel_launch(void* const* d_in, const int* in_sizes, int n_in,
                              void* d_out, int out_size, void* d_ws, size_t ws_size,
                              hipStream_t stream)
{
    (void)in_sizes; (void)n_in; (void)out_size; (void)ws_size;
    const float* hidden   = (const float*)d_in[0];
    const float* mask     = (const float*)d_in[1];
    const float* norm_a_w = (const float*)d_in[2];
    const float* norm_a_b = (const float*)d_in[3];
    const float* proj_a_w = (const float*)d_in[4];
    const float* proj_a_b = (const float*)d_in[5];
    const float* ln_w     = (const float*)d_in[6];
    const float* ln_b     = (const float*)d_in[7];
    const float* Wq       = (const float*)d_in[8];
    const float* Wk       = (const float*)d_in[9];
    const float* Wv       = (const float*)d_in[10];
    const float* Wfa      = (const float*)d_in[11];
    const float* Wfb      = (const float*)d_in[12];
    const float* dt_bias  = (const float*)d_in[13];
    const float* A_log    = (const float*)d_in[14];
    const float* Wb       = (const float*)d_in[15];
    const float* Wga      = (const float*)d_in[16];
    const float* Wgb      = (const float*)d_in[17];
    const float* onorm_w  = (const float*)d_in[18];
    const float* Wo       = (const float*)d_in[19];
    const float* Wgate    = (const float*)d_in[20];
    const float* Wup      = (const float*)d_in[21];
    const float* Wdown    = (const float*)d_in[22];

    // fp32 workspace region
    float* ws    = (float*)d_ws;
    float* hbuf  = ws;                 // 6291456
    float* qb    = ws + HROW;          // 6291456 (o after scan; mg_bf aliases qb..kb)
    float* kb    = ws + 2 * HROW;      // 6291456
    float* vb    = ws + 3 * HROW;      // 6291456 (gate after scan; a_bf aliases)
    float* egb   = ws + 4 * HROW;      // 6291456
    float* betab = ws + 5 * HROW;      // 65536
    // bf16 region
    unsigned short* bfp    = (unsigned short*)(betab + 65536);
    unsigned short* x_bf   = bfp;                 bfp += HROW;            // LN out (o_bf reuses)
    unsigned short* fab_bf = bfp;                 bfp += (size_t)MM * HD;
    unsigned short* wt_proj = bfp;                bfp += 768 * 768;
    unsigned short *wt_q[LL], *wt_k[LL], *wt_v[LL], *wt_o[LL], *wt_fb[LL], *wt_gb[LL],
                   *wt_gate[LL], *wt_up[LL], *wt_down[LL];
    for (int l = 0; l < LL; ++l) {
        wt_q[l] = bfp;    bfp += 768 * 768;
        wt_k[l] = bfp;    bfp += 768 * 768;
        wt_v[l] = bfp;    bfp += 768 * 768;
        wt_o[l] = bfp;    bfp += 768 * 768;
        wt_fb[l] = bfp;   bfp += 768 * 96;
        wt_gb[l] = bfp;   bfp += 768 * 96;
        wt_gate[l] = bfp; bfp += 2048 * 768;
        wt_up[l] = bfp;   bfp += 2048 * 768;
        wt_down[l] = bfp; bfp += 768 * 2048;
    }
    // aliases
    unsigned short* mg_bf = (unsigned short*)qb;   // 8192*2048 bf16 spans qb+part of kb
    unsigned short* a_bf  = (unsigned short*)vb;   // 8192*768 bf16
    unsigned short* o_bf  = x_bf;                  // 8192*768 bf16

    float* out    = (float*)d_out;
    float* states = out + HROW;

    // ---- weight transpose+convert (once per call)
    transcvt<<<dim3(24, 24), 256, 0, stream>>>(proj_a_w, wt_proj, 768, 768);
    for (int l = 0; l < LL; ++l) {
        transcvt<<<dim3(24, 24), 256, 0, stream>>>(Wq + (size_t)l * 589824, wt_q[l], 768, 768);
        transcvt<<<dim3(24, 24), 256, 0, stream>>>(Wk + (size_t)l * 589824, wt_k[l], 768, 768);
        transcvt<<<dim3(24, 24), 256, 0, stream>>>(Wv + (size_t)l * 589824, wt_v[l], 768, 768);
        transcvt<<<dim3(24, 24), 256, 0, stream>>>(Wo + (size_t)l * 589824, wt_o[l], 768, 768);
        transcvt<<<dim3(24, 3), 256, 0, stream>>>(Wfb + (size_t)l * 73728, wt_fb[l], 96, 768);
        transcvt<<<dim3(24, 3), 256, 0, stream>>>(Wgb + (size_t)l * 73728, wt_gb[l], 96, 768);
        transcvt<<<dim3(64, 24), 256, 0, stream>>>(Wgate + (size_t)l * 1572864, wt_gate[l], 768, 2048);
        transcvt<<<dim3(64, 24), 256, 0, stream>>>(Wup + (size_t)l * 1572864, wt_up[l], 768, 2048);
        transcvt<<<dim3(24, 64), 256, 0, stream>>>(Wdown + (size_t)l * 1572864, wt_down[l], 2048, 768);
    }

    // ---- h = LN(hidden) @ proj + b
    layernorm_rows<<<MM, 256, 0, stream>>>(hidden, x_bf, norm_a_w, norm_a_b, nullptr);
    bgemm<BE_BIAS><<<dim3(6, 64), 256, 0, stream>>>(x_bf, wt_proj, hbuf, nullptr,
                                                    proj_a_b, nullptr, MM, DD, DD);

    for (int l = 0; l < LL; ++l) {
        // x = LN(h) * mask  (bf16)
        layernorm_rows<<<MM, 256, 0, stream>>>(hbuf, x_bf, ln_w + l * DD, ln_b + l * DD, mask);
        // q,k,v = silu(x@W)  (f32)
        bgemm<BE_SILU><<<dim3(6, 64), 256, 0, stream>>>(x_bf, wt_q[l], qb, nullptr, nullptr, nullptr, MM, DD, DD);
        bgemm<BE_SILU><<<dim3(6, 64), 256, 0, stream>>>(x_bf, wt_k[l], kb, nullptr, nullptr, nullptr, MM, DD, DD);
        bgemm<BE_SILU><<<dim3(6, 64), 256, 0, stream>>>(x_bf, wt_v[l], vb, nullptr, nullptr, nullptr, MM, DD, DD);
        l2norm_rows<<<(MM * HH) / 4, 256, 0, stream>>>(qb, 0.1020620726159658f);
        l2norm_rows<<<(MM * HH) / 4, 256, 0, stream>>>(kb, 1.f);
        // fa = x@Wfa (bf16), eg = exp(-exp(A_log)*softplus(fa@Wfb + dt_bias)) (f32)
        gemm_small<0><<<dim3(2, 128), 256, 0, stream>>>(x_bf, Wfa + (size_t)l * DD * HD, fab_bf, nullptr, MM, HD, DD);
        bgemm<BE_EG><<<dim3(6, 64), 256, 0, stream>>>(fab_bf, wt_fb[l], egb, nullptr,
                                                      A_log + l * DD, dt_bias + l * DD, MM, DD, HD);
        // beta = sigmoid(x@Wb) (f32)
        gemm_small<1><<<dim3(1, 128), 256, 0, stream>>>(x_bf, Wb + (size_t)l * DD * HH, nullptr, betab, MM, HH, DD);
        // scan
        kda_scan<<<64, 192, 0, stream>>>(qb, kb, vb, egb, betab, qb,
                                         states + (size_t)l * BB * HH * HD * HD);
        // gate = (x@Wga)@Wgb (f32, into vb)
        gemm_small<0><<<dim3(2, 128), 256, 0, stream>>>(x_bf, Wga + (size_t)l * DD * HD, fab_bf, nullptr, MM, HD, DD);
        bgemm<BE_F32><<<dim3(6, 64), 256, 0, stream>>>(fab_bf, wt_gb[l], vb, nullptr, nullptr, nullptr, MM, DD, HD);
        // o_bf = onorm(o) * silu(gate)
        onorm_gate_k<<<(MM * HH) / 4, 256, 0, stream>>>(qb, vb, onorm_w + l * HD, o_bf);
        // a = o @ Wo  (bf16, into vb-space)
        bgemm<BE_BF16><<<dim3(6, 64), 256, 0, stream>>>(o_bf, wt_o[l], nullptr, a_bf, nullptr, nullptr, MM, DD, DD);
        // mg = silu(a@Wgate)*(a@Wup)  (bf16, into qb-space)
        bgemm_dual<<<dim3(32, 64), 256, 0, stream>>>(a_bf, wt_gate[l], wt_up[l], mg_bf, MM, FF, DD);
        // h' = mg@Wdown + h
        float* dst = (l == LL - 1) ? out : hbuf;
        bgemm<BE_RES><<<dim3(6, 64), 256, 0, stream>>>(mg_bf, wt_down[l], dst, nullptr,
                                                       hbuf, nullptr, MM, DD, FF);
    }
}